// Round 4
// baseline (1642.162 us; speedup 1.0000x reference)
//
#include <hip/hip_runtime.h>
#include <math.h>

// ---------------------------------------------------------------------------
// VertexGNN on MI355X — round 3: CSR-by-dst + fully-fused edge+node kernel.
// Wave-per-node: 16-edge MFMA chunks (16x96 @ 96x64 bf16), per-edge LN+GELU
// in C-layout, in-register masked row-sum (no atomics, no agg buffer), fused
// mean/LN/LN/residual node update into double-buffered h.
// ---------------------------------------------------------------------------

typedef __attribute__((ext_vector_type(8))) short bfrag;   // 8 x bf16
typedef __attribute__((ext_vector_type(4))) float ffrag;   // 4 x f32

__device__ __forceinline__ float wave_sum64(float v) {
#pragma unroll
  for (int m = 1; m < 64; m <<= 1) v += __shfl_xor(v, m, 64);
  return v;
}

// sum across the 16 consecutive lanes sharing lane>>4
__device__ __forceinline__ float rsum16(float v) {
#pragma unroll
  for (int m = 1; m < 16; m <<= 1) v += __shfl_xor(v, m, 64);
  return v;
}

__device__ __forceinline__ float ln_apply(float t, float g, float b) {
  float mu = wave_sum64(t) * 0.015625f;
  float d = t - mu;
  float var = wave_sum64(d * d) * 0.015625f;
  return d * rsqrtf(var + 1e-5f) * g + b;
}

__device__ __forceinline__ float gelu_exact(float v) {
  return 0.5f * v * (1.0f + erff(v * 0.70710678118654752440f));
}

__device__ __forceinline__ float lane_bcast(float v, int k) {
  return __uint_as_float(__builtin_amdgcn_readlane(__float_as_uint(v), k));
}

// float -> bf16 (RNE)
__device__ __forceinline__ short f2bf(float f) {
  union { float f; unsigned u; } v; v.f = f;
  unsigned r = v.u + 0x7fffu + ((v.u >> 16) & 1u);
  return (short)(r >> 16);
}

// --------------------------- weight prep -----------------------------------
// Wt[l][f][k] = (k<66 ? conv_w[l][k][f] : 0) as bf16; shape 3 x 64 x 96.
__global__ void k_prep_w(const float* __restrict__ conv_w, ushort* __restrict__ wt) {
  int i = blockIdx.x * blockDim.x + threadIdx.x;
  if (i >= 3 * 64 * 96) return;
  int k = i % 96, f = (i / 96) % 64, l = i / (96 * 64);
  float v = (k < 66) ? conv_w[(size_t)l * 66 * 64 + k * 64 + f] : 0.0f;
  wt[i] = (ushort)f2bf(v);
}

// --------------------------- node embedding --------------------------------
__global__ void k_node_embed(const float* __restrict__ x,
                             const float* __restrict__ w1, const float* __restrict__ b1,
                             const float* __restrict__ g1, const float* __restrict__ be1,
                             const float* __restrict__ w2, const float* __restrict__ b2,
                             const float* __restrict__ g2, const float* __restrict__ be2,
                             float* __restrict__ h, int n_nodes) {
  const int lane = threadIdx.x & 63;
  const int wid = (blockIdx.x * blockDim.x + threadIdx.x) >> 6;
  const int nw = (gridDim.x * blockDim.x) >> 6;
  float wc[64];
#pragma unroll
  for (int k = 0; k < 64; k++) wc[k] = w2[k * 64 + lane];
  const float w1a = w1[lane], w1b = w1[64 + lane];
  const float vb1 = b1[lane], vg1 = g1[lane], vbe1 = be1[lane];
  const float vb2 = b2[lane], vg2 = g2[lane], vbe2 = be2[lane];
  for (int n = wid; n < n_nodes; n += nw) {
    const float x0 = x[2 * n], x1 = x[2 * n + 1];
    float t = fmaf(x0, w1a, fmaf(x1, w1b, vb1));
    t = gelu_exact(ln_apply(t, vg1, vbe1));
    float a0 = vb2, a1 = 0.f, a2 = 0.f, a3 = 0.f;
#pragma unroll
    for (int k = 0; k < 64; k += 4) {
      a0 = fmaf(lane_bcast(t, k + 0), wc[k + 0], a0);
      a1 = fmaf(lane_bcast(t, k + 1), wc[k + 1], a1);
      a2 = fmaf(lane_bcast(t, k + 2), wc[k + 2], a2);
      a3 = fmaf(lane_bcast(t, k + 3), wc[k + 3], a3);
    }
    float acc = (a0 + a1) + (a2 + a3);
    acc = gelu_exact(ln_apply(acc, vg2, vbe2));
    h[n * 64 + lane] = acc;
  }
}

// ----------------------------- CSR build -----------------------------------
__global__ void k_hist(const int* __restrict__ ei, int* __restrict__ cnts, int ne) {
  int i = blockIdx.x * blockDim.x + threadIdx.x;
  if (i < ne) atomicAdd(&cnts[ei[ne + i]], 1);
}

// In-place exclusive scan, single block of 1024 threads (16 waves).
__global__ __launch_bounds__(1024) void k_scan_excl(int* __restrict__ buf, int n) {
  __shared__ int wsum[16];
  __shared__ int carry_s;
  const int tid = threadIdx.x, lane = tid & 63, w = tid >> 6;
  if (tid == 0) carry_s = 0;
  __syncthreads();
  for (int base = 0; base < n; base += 1024) {
    const int i = base + tid;
    int v = (i < n) ? buf[i] : 0;
    int inc = v;
#pragma unroll
    for (int s = 1; s < 64; s <<= 1) {
      int t = __shfl_up(inc, s, 64);
      if (lane >= s) inc += t;
    }
    if (lane == 63) wsum[w] = inc;
    __syncthreads();
    int wb = 0;
    for (int j = 0; j < w; j++) wb += wsum[j];
    const int carry = carry_s;
    if (i < n) buf[i] = carry + wb + inc - v;  // exclusive
    __syncthreads();
    if (tid == 1023) carry_s = carry + wb + inc;
    __syncthreads();
  }
}

// scatter edge ids into dst-buckets; cursor[] (== offsets) becomes ends[].
__global__ void k_scatter(const int* __restrict__ ei, int* __restrict__ cursor,
                          int* __restrict__ elist, int ne) {
  int i = blockIdx.x * blockDim.x + threadIdx.x;
  if (i < ne) {
    const int d = ei[ne + i];
    const int pos = atomicAdd(&cursor[d], 1);
    elist[pos] = i;
  }
}

// ---------------- fused edge-message + aggregate + node update --------------
// Wave per node. Chunks of 16 edges: A: 16x96 (rows=edges, k=[h[src]|ea|pad]),
// B: Wt 96x64. C: row=edge=(lane>>4)*4+r, col=feat=16t+(lane&15).
__global__ __launch_bounds__(256) void k_edge_node(
    const float* __restrict__ h_in, float* __restrict__ h_out,
    const float* __restrict__ ea, const int* __restrict__ ei,
    const int* __restrict__ elist, const int* __restrict__ ends,
    const ushort* __restrict__ wt,
    const float* __restrict__ bias, const float* __restrict__ mg,
    const float* __restrict__ mb,
    const float* __restrict__ ng, const float* __restrict__ nb,
    const float* __restrict__ og, const float* __restrict__ ob,
    int n_nodes, int ne) {
  const int lane = threadIdx.x & 63;
  const int grp = lane >> 4, col = lane & 15;
  const int wid = (blockIdx.x * blockDim.x + threadIdx.x) >> 6;
  const int nw = (gridDim.x * blockDim.x) >> 6;

  bfrag Bf[3][4];
#pragma unroll
  for (int s = 0; s < 3; s++)
#pragma unroll
    for (int t = 0; t < 4; t++)
      Bf[s][t] = *(const bfrag*)(wt + (size_t)(t * 16 + col) * 96 + s * 32 + grp * 8);

  float vb[4], vg[4], vbb[4], vng[4], vnb[4], vog[4], vob[4];
#pragma unroll
  for (int t = 0; t < 4; t++) {
    const int f = t * 16 + col;
    vb[t] = bias[f]; vg[t] = mg[f]; vbb[t] = mb[f];
    vng[t] = ng[f];  vnb[t] = nb[f];
    vog[t] = og[f];  vob[t] = ob[f];
  }

  for (int n = wid; n < n_nodes; n += nw) {
    const int start = (n == 0) ? 0 : ends[n - 1];
    const int end = ends[n];
    float aggf[4] = {0.f, 0.f, 0.f, 0.f};

    for (int p = start; p < end; p += 16) {
      const int rem = min(16, end - p);
      // ---- A fragments: this lane feeds edge row m = col ----
      const int e = elist[p + min(col, rem - 1)];
      const int src = ei[e];
      const float* hp = h_in + (size_t)src * 64 + grp * 8;
      const float4 f0 = *(const float4*)(hp);
      const float4 f1 = *(const float4*)(hp + 4);
      const float4 f2 = *(const float4*)(hp + 32);
      const float4 f3 = *(const float4*)(hp + 36);
      bfrag A0, A1;
      A0[0] = f2bf(f0.x); A0[1] = f2bf(f0.y); A0[2] = f2bf(f0.z); A0[3] = f2bf(f0.w);
      A0[4] = f2bf(f1.x); A0[5] = f2bf(f1.y); A0[6] = f2bf(f1.z); A0[7] = f2bf(f1.w);
      A1[0] = f2bf(f2.x); A1[1] = f2bf(f2.y); A1[2] = f2bf(f2.z); A1[3] = f2bf(f2.w);
      A1[4] = f2bf(f3.x); A1[5] = f2bf(f3.y); A1[6] = f2bf(f3.z); A1[7] = f2bf(f3.w);
      bfrag A2 = {0, 0, 0, 0, 0, 0, 0, 0};
      if (grp == 0) {
        const float2 eav = *(const float2*)(ea + 2 * (size_t)e);
        A2[0] = f2bf(eav.x); A2[1] = f2bf(eav.y);
      }

      ffrag acc[4];
#pragma unroll
      for (int t = 0; t < 4; t++) { ffrag c = {vb[t], vb[t], vb[t], vb[t]}; acc[t] = c; }
#pragma unroll
      for (int t = 0; t < 4; t++)
        acc[t] = __builtin_amdgcn_mfma_f32_16x16x32_bf16(A0, Bf[0][t], acc[t], 0, 0, 0);
#pragma unroll
      for (int t = 0; t < 4; t++)
        acc[t] = __builtin_amdgcn_mfma_f32_16x16x32_bf16(A1, Bf[1][t], acc[t], 0, 0, 0);
#pragma unroll
      for (int t = 0; t < 4; t++)
        acc[t] = __builtin_amdgcn_mfma_f32_16x16x32_bf16(A2, Bf[2][t], acc[t], 0, 0, 0);

      // ---- per-edge LayerNorm over 64 features (rows m = grp*4+r) ----
      float mu[4], inv[4];
#pragma unroll
      for (int r = 0; r < 4; r++) {
        float s = ((acc[0][r] + acc[1][r]) + (acc[2][r] + acc[3][r]));
        mu[r] = rsum16(s) * 0.015625f;
      }
#pragma unroll
      for (int r = 0; r < 4; r++) {
        float d0 = acc[0][r] - mu[r], d1 = acc[1][r] - mu[r];
        float d2 = acc[2][r] - mu[r], d3 = acc[3][r] - mu[r];
        float q = (d0 * d0 + d1 * d1) + (d2 * d2 + d3 * d3);
        inv[r] = rsqrtf(rsum16(q) * 0.015625f + 1e-5f);
      }

      // ---- GELU + masked in-register row-sum (aggregate over edges) ----
#pragma unroll
      for (int t = 0; t < 4; t++) {
        float rs = 0.f;
#pragma unroll
        for (int r = 0; r < 4; r++) {
          float v = (acc[t][r] - mu[r]) * inv[r] * vg[t] + vbb[t];
          v = gelu_exact(v);
          rs += (grp * 4 + r < rem) ? v : 0.f;
        }
        rs += __shfl_xor(rs, 16, 64);
        rs += __shfl_xor(rs, 32, 64);   // all grps now hold full 16-row sum
        aggf[t] += rs;
      }
    }

    // ---- fused node update: ln(agg/deg + h) -> ln -> residual ----
    const float dg = fmaxf((float)(end - start), 1.0f);
    float hv[4], a[4];
#pragma unroll
    for (int t = 0; t < 4; t++) hv[t] = h_in[(size_t)n * 64 + t * 16 + col];
#pragma unroll
    for (int t = 0; t < 4; t++) a[t] = aggf[t] / dg + hv[t];

    float s1 = (a[0] + a[1]) + (a[2] + a[3]);
    float mu1 = rsum16(s1) * 0.015625f;
    float q1 = 0.f;
#pragma unroll
    for (int t = 0; t < 4; t++) { float d = a[t] - mu1; q1 += d * d; }
    float inv1 = rsqrtf(rsum16(q1) * 0.015625f + 1e-5f);
    float c[4];
#pragma unroll
    for (int t = 0; t < 4; t++) c[t] = (a[t] - mu1) * inv1 * vng[t] + vnb[t];

    float s2 = (c[0] + c[1]) + (c[2] + c[3]);
    float mu2 = rsum16(s2) * 0.015625f;
    float q2 = 0.f;
#pragma unroll
    for (int t = 0; t < 4; t++) { float d = c[t] - mu2; q2 += d * d; }
    float inv2 = rsqrtf(rsum16(q2) * 0.015625f + 1e-5f);
    float outv[4];
#pragma unroll
    for (int t = 0; t < 4; t++)
      outv[t] = hv[t] + ((c[t] - mu2) * inv2 * vog[t] + vob[t]);

    // coalesced store: lane writes feature `lane` = tile grp, col lane&15
    float sel = (grp == 0) ? outv[0] : (grp == 1) ? outv[1]
              : (grp == 2) ? outv[2] : outv[3];
    h_out[(size_t)n * 64 + lane] = sel;
  }
}

// ------------------------------ pooling (segmented) -------------------------
__global__ void k_pool_seg(const float* __restrict__ h, const int* __restrict__ batch,
                           float* __restrict__ g, float* __restrict__ cnt,
                           int n_nodes, int chunk) {
  const int lane = threadIdx.x & 63;
  const int wid = (blockIdx.x * blockDim.x + threadIdx.x) >> 6;
  const int n0 = wid * chunk;
  if (n0 >= n_nodes) return;
  const int n1 = min(n0 + chunk, n_nodes);
  int cur = batch[n0], c = 0;
  float acc = 0.f;
  for (int n = n0; n < n1; n++) {
    const int b = batch[n];
    if (b != cur) {
      atomicAdd(&g[(size_t)cur * 64 + lane], acc);
      if (lane == 0) atomicAdd(&cnt[cur], (float)c);
      acc = 0.f; c = 0; cur = b;
    }
    acc += h[(size_t)n * 64 + lane];
    c++;
  }
  atomicAdd(&g[(size_t)cur * 64 + lane], acc);
  if (lane == 0) atomicAdd(&cnt[cur], (float)c);
}

// ------------------------------- head --------------------------------------
__global__ void k_head(const float* __restrict__ g, const float* __restrict__ cnt,
                       const float* __restrict__ w1, const float* __restrict__ b1,
                       const float* __restrict__ g1, const float* __restrict__ be1,
                       const float* __restrict__ w2, const float* __restrict__ b2,
                       const float* __restrict__ g2, const float* __restrict__ be2,
                       const float* __restrict__ w3, const float* __restrict__ b3,
                       float* __restrict__ out, int nb_) {
  const int lane = threadIdx.x & 63;
  const int row = (blockIdx.x * blockDim.x + threadIdx.x) >> 6;
  if (row >= nb_) return;
  const float c = fmaxf(cnt[row], 1.0f);
  const float gv = g[row * 64 + lane] / c;
  float a0 = b1[lane], a1 = 0.f, a2 = 0.f, a3 = 0.f;
#pragma unroll
  for (int k = 0; k < 64; k += 4) {
    a0 = fmaf(lane_bcast(gv, k + 0), w1[(k + 0) * 64 + lane], a0);
    a1 = fmaf(lane_bcast(gv, k + 1), w1[(k + 1) * 64 + lane], a1);
    a2 = fmaf(lane_bcast(gv, k + 2), w1[(k + 2) * 64 + lane], a2);
    a3 = fmaf(lane_bcast(gv, k + 3), w1[(k + 3) * 64 + lane], a3);
  }
  float t = (a0 + a1) + (a2 + a3);
  t = fmaxf(ln_apply(t, g1[lane], be1[lane]), 0.0f);

  const int j = lane & 31;
  float c0 = b2[j], c1 = 0.f, c2 = 0.f, c3 = 0.f;
#pragma unroll
  for (int k = 0; k < 64; k += 4) {
    c0 = fmaf(lane_bcast(t, k + 0), w2[(k + 0) * 32 + j], c0);
    c1 = fmaf(lane_bcast(t, k + 1), w2[(k + 1) * 32 + j], c1);
    c2 = fmaf(lane_bcast(t, k + 2), w2[(k + 2) * 32 + j], c2);
    c3 = fmaf(lane_bcast(t, k + 3), w2[(k + 3) * 32 + j], c3);
  }
  float t2 = (c0 + c1) + (c2 + c3);
  t2 = fmaxf(ln_apply(t2, g2[j], be2[j]), 0.0f);
  const float p = t2 * w3[j];
  const float s = wave_sum64(p) * 0.5f;
  if (lane == 0) out[row] = s + b3[0];
}

// ---------------------------------------------------------------------------
extern "C" void kernel_launch(void* const* d_in, const int* in_sizes, int n_in,
                              void* d_out, int out_size, void* d_ws, size_t ws_size,
                              hipStream_t stream) {
  const float* x      = (const float*)d_in[0];
  const float* ea     = (const float*)d_in[1];
  const float* ne_w1  = (const float*)d_in[2];
  const float* ne_b1  = (const float*)d_in[3];
  const float* ne_g1  = (const float*)d_in[4];
  const float* ne_be1 = (const float*)d_in[5];
  const float* ne_w2  = (const float*)d_in[6];
  const float* ne_b2  = (const float*)d_in[7];
  const float* ne_g2  = (const float*)d_in[8];
  const float* ne_be2 = (const float*)d_in[9];
  const float* conv_w = (const float*)d_in[10];
  const float* conv_b = (const float*)d_in[11];
  const float* conv_mg= (const float*)d_in[12];
  const float* conv_mb= (const float*)d_in[13];
  const float* conv_ng= (const float*)d_in[14];
  const float* conv_nb= (const float*)d_in[15];
  const float* out_ng = (const float*)d_in[16];
  const float* out_nb = (const float*)d_in[17];
  const float* m_w1   = (const float*)d_in[18];
  const float* m_b1   = (const float*)d_in[19];
  const float* m_g1   = (const float*)d_in[20];
  const float* m_be1  = (const float*)d_in[21];
  const float* m_w2   = (const float*)d_in[22];
  const float* m_b2   = (const float*)d_in[23];
  const float* m_g2   = (const float*)d_in[24];
  const float* m_be2  = (const float*)d_in[25];
  const float* m_w3   = (const float*)d_in[26];
  const float* m_b3   = (const float*)d_in[27];
  const int*   eidx   = (const int*)d_in[28];
  const int*   batch  = (const int*)d_in[29];
  float* outp = (float*)d_out;

  const int NN = in_sizes[29];
  const int NE = in_sizes[1] / 2;
  const int NB = out_size;

  float* ws = (float*)d_ws;
  float*  h0   = ws;                                  // NN*64 f32
  float*  h1   = h0 + (size_t)NN * 64;                // NN*64 f32
  float*  gbuf = h1 + (size_t)NN * 64;                // NB*64 f32
  float*  cnt  = gbuf + (size_t)NB * 64;              // NB f32
  ushort* wt   = (ushort*)(cnt + NB);                 // 3*64*96 bf16 (36 KB)
  int*    csr  = (int*)(wt + 3 * 64 * 96);            // NN int
  int*    elist= csr + NN;                            // NE int

  // zero gbuf+cnt (contiguous) and csr
  hipMemsetAsync(gbuf, 0, sizeof(float) * ((size_t)NB * 64 + NB), stream);
  hipMemsetAsync(csr, 0, sizeof(int) * (size_t)NN, stream);

  const dim3 blk(256);
  k_prep_w<<<(3 * 64 * 96 + 255) / 256, blk, 0, stream>>>(conv_w, wt);
  k_node_embed<<<2048, blk, 0, stream>>>(x, ne_w1, ne_b1, ne_g1, ne_be1,
                                         ne_w2, ne_b2, ne_g2, ne_be2, h0, NN);
  k_hist<<<(NE + 255) / 256, blk, 0, stream>>>(eidx, csr, NE);
  k_scan_excl<<<1, 1024, 0, stream>>>(csr, NN);
  k_scatter<<<(NE + 255) / 256, blk, 0, stream>>>(eidx, csr, elist, NE);

  float* hin = h0;
  float* hout = h1;
  for (int l = 0; l < 3; l++) {
    k_edge_node<<<4096, blk, 0, stream>>>(
        hin, hout, ea, eidx, elist, csr, wt + (size_t)l * 64 * 96,
        conv_b + l * 64, conv_mg + l * 64, conv_mb + l * 64,
        conv_ng + l * 64, conv_nb + l * 64,
        out_ng + l * 64, out_nb + l * 64, NN, NE);
    float* tmp = hin; hin = hout; hout = tmp;
  }
  // after 3 layers the latest h is in `hin`

  {
    const int chunk = 64;
    const int nwaves = (NN + chunk - 1) / chunk;
    const int nblocks = (nwaves * 64 + 255) / 256;
    k_pool_seg<<<nblocks, blk, 0, stream>>>(hin, batch, gbuf, cnt, NN, chunk);
  }
  k_head<<<(NB + 3) / 4, blk, 0, stream>>>(gbuf, cnt, m_w1, m_b1, m_g1, m_be1,
                                           m_w2, m_b2, m_g2, m_be2, m_w3, m_b3,
                                           outp, NB);
}

// Round 5
// 1108.092 us; speedup vs baseline: 1.4820x; 1.4820x over previous
//
#include <hip/hip_runtime.h>
#include <math.h>

// ---------------------------------------------------------------------------
// VertexGNN on MI355X — round 4: latency-chain + VALU diet.
// - edata[pos]={src, bf16x2(ea)} packed at CSR build: 1 coalesced load + 1
//   gather per edge (was elist->ei->h 3-deep chain, uncoalesced ea).
// - bf16 shadow hb for MFMA gathers (half bytes, no f2bf in hot loop).
// - branchless A&S erf (~12 VALU) instead of libm erff.
// - two-pass O(3-barrier) scan instead of 98-iteration serial scan.
// ---------------------------------------------------------------------------

typedef __attribute__((ext_vector_type(8))) short bfrag;   // 8 x bf16
typedef __attribute__((ext_vector_type(4))) float ffrag;   // 4 x f32

__device__ __forceinline__ float wave_sum64(float v) {
#pragma unroll
  for (int m = 1; m < 64; m <<= 1) v += __shfl_xor(v, m, 64);
  return v;
}

__device__ __forceinline__ float rsum16(float v) {
#pragma unroll
  for (int m = 1; m < 16; m <<= 1) v += __shfl_xor(v, m, 64);
  return v;
}

__device__ __forceinline__ float ln_apply(float t, float g, float b) {
  float mu = wave_sum64(t) * 0.015625f;
  float d = t - mu;
  float var = wave_sum64(d * d) * 0.015625f;
  return d * rsqrtf(var + 1e-5f) * g + b;
}

// branchless erf, Abramowitz-Stegun 7.1.26, |err| <= 1.5e-7
__device__ __forceinline__ float erf_fast(float x) {
  float ax = fabsf(x);
  float t = __builtin_amdgcn_rcpf(fmaf(0.3275911f, ax, 1.0f));
  float p = t * fmaf(t, fmaf(t, fmaf(t, fmaf(t, 1.061405429f, -1.453152027f),
                                     1.421413741f), -0.284496736f), 0.254829592f);
  float e = __expf(-ax * ax);
  float r = fmaf(-p, e, 1.0f);
  return copysignf(r, x);
}

__device__ __forceinline__ float gelu_exact(float v) {
  return 0.5f * v * (1.0f + erf_fast(v * 0.70710678118654752440f));
}

__device__ __forceinline__ float lane_bcast(float v, int k) {
  return __uint_as_float(__builtin_amdgcn_readlane(__float_as_uint(v), k));
}

// float -> bf16 (RNE)
__device__ __forceinline__ short f2bf(float f) {
  union { float f; unsigned u; } v; v.f = f;
  unsigned r = v.u + 0x7fffu + ((v.u >> 16) & 1u);
  return (short)(r >> 16);
}

// --------------------------- weight prep -----------------------------------
__global__ void k_prep_w(const float* __restrict__ conv_w, ushort* __restrict__ wt) {
  int i = blockIdx.x * blockDim.x + threadIdx.x;
  if (i >= 3 * 64 * 96) return;
  int k = i % 96, f = (i / 96) % 64, l = i / (96 * 64);
  float v = (k < 66) ? conv_w[(size_t)l * 66 * 64 + k * 64 + f] : 0.0f;
  wt[i] = (ushort)f2bf(v);
}

// --------------------------- node embedding --------------------------------
__global__ void k_node_embed(const float* __restrict__ x,
                             const float* __restrict__ w1, const float* __restrict__ b1,
                             const float* __restrict__ g1, const float* __restrict__ be1,
                             const float* __restrict__ w2, const float* __restrict__ b2,
                             const float* __restrict__ g2, const float* __restrict__ be2,
                             float* __restrict__ h, ushort* __restrict__ hb, int n_nodes) {
  const int lane = threadIdx.x & 63;
  const int wid = (blockIdx.x * blockDim.x + threadIdx.x) >> 6;
  const int nw = (gridDim.x * blockDim.x) >> 6;
  float wc[64];
#pragma unroll
  for (int k = 0; k < 64; k++) wc[k] = w2[k * 64 + lane];
  const float w1a = w1[lane], w1b = w1[64 + lane];
  const float vb1 = b1[lane], vg1 = g1[lane], vbe1 = be1[lane];
  const float vb2 = b2[lane], vg2 = g2[lane], vbe2 = be2[lane];
  for (int n = wid; n < n_nodes; n += nw) {
    const float x0 = x[2 * n], x1 = x[2 * n + 1];
    float t = fmaf(x0, w1a, fmaf(x1, w1b, vb1));
    t = gelu_exact(ln_apply(t, vg1, vbe1));
    float a0 = vb2, a1 = 0.f, a2 = 0.f, a3 = 0.f;
#pragma unroll
    for (int k = 0; k < 64; k += 4) {
      a0 = fmaf(lane_bcast(t, k + 0), wc[k + 0], a0);
      a1 = fmaf(lane_bcast(t, k + 1), wc[k + 1], a1);
      a2 = fmaf(lane_bcast(t, k + 2), wc[k + 2], a2);
      a3 = fmaf(lane_bcast(t, k + 3), wc[k + 3], a3);
    }
    float acc = (a0 + a1) + (a2 + a3);
    acc = gelu_exact(ln_apply(acc, vg2, vbe2));
    h[n * 64 + lane] = acc;
    hb[n * 64 + lane] = (ushort)f2bf(acc);
  }
}

// ----------------------------- CSR build -----------------------------------
__global__ void k_hist(const int* __restrict__ ei, int* __restrict__ cnts, int ne) {
  int i = blockIdx.x * blockDim.x + threadIdx.x;
  if (i < ne) atomicAdd(&cnts[ei[ne + i]], 1);
}

// Two-pass exclusive scan, single block 1024 threads, ~3 barriers total.
__global__ __launch_bounds__(1024) void k_scan_fast(int* __restrict__ buf, int n) {
  __shared__ int wsum[16];
  const int tid = threadIdx.x, lane = tid & 63, w = tid >> 6;
  const int chunk = (n + 1023) / 1024;
  const int a = min(tid * chunk, n), b = min(a + chunk, n);
  int s = 0;
  for (int i = a; i < b; i++) s += buf[i];
  int inc = s;
#pragma unroll
  for (int sh = 1; sh < 64; sh <<= 1) {
    int t = __shfl_up(inc, sh, 64);
    if (lane >= sh) inc += t;
  }
  if (lane == 63) wsum[w] = inc;
  __syncthreads();
  int wb = 0;
  for (int j = 0; j < w; j++) wb += wsum[j];
  int excl = wb + inc - s;
  for (int i = a; i < b; i++) { int v = buf[i]; buf[i] = excl; excl += v; }
}

// scatter packed edge payload into dst-buckets; cursor becomes ends[].
__global__ void k_scatter(const int* __restrict__ ei, const float* __restrict__ ea,
                          int* __restrict__ cursor, int2* __restrict__ edata, int ne) {
  int i = blockIdx.x * blockDim.x + threadIdx.x;
  if (i < ne) {
    const int d = ei[ne + i];
    const int s = ei[i];
    const float2 eav = *(const float2*)(ea + 2 * (size_t)i);
    const unsigned pk = (unsigned)(ushort)f2bf(eav.x) |
                        ((unsigned)(ushort)f2bf(eav.y) << 16);
    const int pos = atomicAdd(&cursor[d], 1);
    edata[pos] = make_int2(s, (int)pk);
  }
}

// ---------------- fused edge-message + aggregate + node update --------------
__global__ __launch_bounds__(256) void k_edge_node(
    const float* __restrict__ h_in, const ushort* __restrict__ hb_in,
    float* __restrict__ h_out, ushort* __restrict__ hb_out,
    const int2* __restrict__ edata, const int* __restrict__ ends,
    const ushort* __restrict__ wt,
    const float* __restrict__ bias, const float* __restrict__ mg,
    const float* __restrict__ mb,
    const float* __restrict__ ng, const float* __restrict__ nb,
    const float* __restrict__ og, const float* __restrict__ ob,
    int n_nodes) {
  const int lane = threadIdx.x & 63;
  const int grp = lane >> 4, col = lane & 15;
  const int wid = (blockIdx.x * blockDim.x + threadIdx.x) >> 6;
  const int nw = (gridDim.x * blockDim.x) >> 6;

  bfrag Bf[3][4];
#pragma unroll
  for (int s = 0; s < 3; s++)
#pragma unroll
    for (int t = 0; t < 4; t++)
      Bf[s][t] = *(const bfrag*)(wt + (size_t)(t * 16 + col) * 96 + s * 32 + grp * 8);

  float vb[4], vg[4], vbb[4];
#pragma unroll
  for (int t = 0; t < 4; t++) {
    const int f = t * 16 + col;
    vb[t] = bias[f]; vg[t] = mg[f]; vbb[t] = mb[f];
  }

  for (int n = wid; n < n_nodes; n += nw) {
    const int start = (n == 0) ? 0 : ends[n - 1];
    const int end = ends[n];
    float aggf[4] = {0.f, 0.f, 0.f, 0.f};

    for (int p = start; p < end; p += 16) {
      const int rem = min(16, end - p);
      const int2 ed = edata[p + min(col, rem - 1)];   // coalesced 8B
      const int src = ed.x;
      const ushort* hp = hb_in + (size_t)src * 64 + grp * 8;
      const bfrag A0 = *(const bfrag*)(hp);           // k = grp*8..+7
      const bfrag A1 = *(const bfrag*)(hp + 32);      // k = 32+grp*8..+7
      bfrag A2 = {0, 0, 0, 0, 0, 0, 0, 0};
      if (grp == 0) {
        A2[0] = (short)(ed.y & 0xffff);
        A2[1] = (short)((unsigned)ed.y >> 16);
      }

      ffrag acc[4];
#pragma unroll
      for (int t = 0; t < 4; t++) { ffrag c = {vb[t], vb[t], vb[t], vb[t]}; acc[t] = c; }
#pragma unroll
      for (int t = 0; t < 4; t++)
        acc[t] = __builtin_amdgcn_mfma_f32_16x16x32_bf16(A0, Bf[0][t], acc[t], 0, 0, 0);
#pragma unroll
      for (int t = 0; t < 4; t++)
        acc[t] = __builtin_amdgcn_mfma_f32_16x16x32_bf16(A1, Bf[1][t], acc[t], 0, 0, 0);
#pragma unroll
      for (int t = 0; t < 4; t++)
        acc[t] = __builtin_amdgcn_mfma_f32_16x16x32_bf16(A2, Bf[2][t], acc[t], 0, 0, 0);

      // per-edge LayerNorm over 64 features (rows m = grp*4+r)
      float mu[4], inv[4];
#pragma unroll
      for (int r = 0; r < 4; r++) {
        float s = ((acc[0][r] + acc[1][r]) + (acc[2][r] + acc[3][r]));
        mu[r] = rsum16(s) * 0.015625f;
      }
#pragma unroll
      for (int r = 0; r < 4; r++) {
        float d0 = acc[0][r] - mu[r], d1 = acc[1][r] - mu[r];
        float d2 = acc[2][r] - mu[r], d3 = acc[3][r] - mu[r];
        float q = (d0 * d0 + d1 * d1) + (d2 * d2 + d3 * d3);
        inv[r] = rsqrtf(rsum16(q) * 0.015625f + 1e-5f);
      }

      // GELU + masked in-register row-sum
#pragma unroll
      for (int t = 0; t < 4; t++) {
        float rs = 0.f;
#pragma unroll
        for (int r = 0; r < 4; r++) {
          float v = (acc[t][r] - mu[r]) * inv[r] * vg[t] + vbb[t];
          v = gelu_exact(v);
          rs += (grp * 4 + r < rem) ? v : 0.f;
        }
        rs += __shfl_xor(rs, 16, 64);
        rs += __shfl_xor(rs, 32, 64);
        aggf[t] += rs;
      }
    }

    // bring agg to feature=lane layout (lane = grp*16+col holds t=grp)
    const float aggl = (grp == 0) ? aggf[0] : (grp == 1) ? aggf[1]
                     : (grp == 2) ? aggf[2] : aggf[3];

    // fused node update in lane-feature layout
    const float dg = fmaxf((float)(end - start), 1.0f);
    const float hv = h_in[(size_t)n * 64 + lane];
    const float a = aggl / dg + hv;
    const float c = ln_apply(a, ng[lane], nb[lane]);
    const float o = ln_apply(c, og[lane], ob[lane]);
    const float outv = hv + o;
    h_out[(size_t)n * 64 + lane] = outv;
    hb_out[(size_t)n * 64 + lane] = (ushort)f2bf(outv);
  }
}

// ------------------------------ pooling (segmented) -------------------------
__global__ void k_pool_seg(const float* __restrict__ h, const int* __restrict__ batch,
                           float* __restrict__ g, float* __restrict__ cnt,
                           int n_nodes, int chunk) {
  const int lane = threadIdx.x & 63;
  const int wid = (blockIdx.x * blockDim.x + threadIdx.x) >> 6;
  const int n0 = wid * chunk;
  if (n0 >= n_nodes) return;
  const int n1 = min(n0 + chunk, n_nodes);
  int cur = batch[n0], c = 0;
  float acc = 0.f;
  for (int n = n0; n < n1; n++) {
    const int b = batch[n];
    if (b != cur) {
      atomicAdd(&g[(size_t)cur * 64 + lane], acc);
      if (lane == 0) atomicAdd(&cnt[cur], (float)c);
      acc = 0.f; c = 0; cur = b;
    }
    acc += h[(size_t)n * 64 + lane];
    c++;
  }
  atomicAdd(&g[(size_t)cur * 64 + lane], acc);
  if (lane == 0) atomicAdd(&cnt[cur], (float)c);
}

// ------------------------------- head --------------------------------------
__global__ void k_head(const float* __restrict__ g, const float* __restrict__ cnt,
                       const float* __restrict__ w1, const float* __restrict__ b1,
                       const float* __restrict__ g1, const float* __restrict__ be1,
                       const float* __restrict__ w2, const float* __restrict__ b2,
                       const float* __restrict__ g2, const float* __restrict__ be2,
                       const float* __restrict__ w3, const float* __restrict__ b3,
                       float* __restrict__ out, int nb_) {
  const int lane = threadIdx.x & 63;
  const int row = (blockIdx.x * blockDim.x + threadIdx.x) >> 6;
  if (row >= nb_) return;
  const float c = fmaxf(cnt[row], 1.0f);
  const float gv = g[row * 64 + lane] / c;
  float a0 = b1[lane], a1 = 0.f, a2 = 0.f, a3 = 0.f;
#pragma unroll
  for (int k = 0; k < 64; k += 4) {
    a0 = fmaf(lane_bcast(gv, k + 0), w1[(k + 0) * 64 + lane], a0);
    a1 = fmaf(lane_bcast(gv, k + 1), w1[(k + 1) * 64 + lane], a1);
    a2 = fmaf(lane_bcast(gv, k + 2), w1[(k + 2) * 64 + lane], a2);
    a3 = fmaf(lane_bcast(gv, k + 3), w1[(k + 3) * 64 + lane], a3);
  }
  float t = (a0 + a1) + (a2 + a3);
  t = fmaxf(ln_apply(t, g1[lane], be1[lane]), 0.0f);

  const int j = lane & 31;
  float c0 = b2[j], c1 = 0.f, c2 = 0.f, c3 = 0.f;
#pragma unroll
  for (int k = 0; k < 64; k += 4) {
    c0 = fmaf(lane_bcast(t, k + 0), w2[(k + 0) * 32 + j], c0);
    c1 = fmaf(lane_bcast(t, k + 1), w2[(k + 1) * 32 + j], c1);
    c2 = fmaf(lane_bcast(t, k + 2), w2[(k + 2) * 32 + j], c2);
    c3 = fmaf(lane_bcast(t, k + 3), w2[(k + 3) * 32 + j], c3);
  }
  float t2 = (c0 + c1) + (c2 + c3);
  t2 = fmaxf(ln_apply(t2, g2[j], be2[j]), 0.0f);
  const float p = t2 * w3[j];
  const float s = wave_sum64(p) * 0.5f;
  if (lane == 0) out[row] = s + b3[0];
}

// ---------------------------------------------------------------------------
extern "C" void kernel_launch(void* const* d_in, const int* in_sizes, int n_in,
                              void* d_out, int out_size, void* d_ws, size_t ws_size,
                              hipStream_t stream) {
  const float* x      = (const float*)d_in[0];
  const float* ea     = (const float*)d_in[1];
  const float* ne_w1  = (const float*)d_in[2];
  const float* ne_b1  = (const float*)d_in[3];
  const float* ne_g1  = (const float*)d_in[4];
  const float* ne_be1 = (const float*)d_in[5];
  const float* ne_w2  = (const float*)d_in[6];
  const float* ne_b2  = (const float*)d_in[7];
  const float* ne_g2  = (const float*)d_in[8];
  const float* ne_be2 = (const float*)d_in[9];
  const float* conv_w = (const float*)d_in[10];
  const float* conv_b = (const float*)d_in[11];
  const float* conv_mg= (const float*)d_in[12];
  const float* conv_mb= (const float*)d_in[13];
  const float* conv_ng= (const float*)d_in[14];
  const float* conv_nb= (const float*)d_in[15];
  const float* out_ng = (const float*)d_in[16];
  const float* out_nb = (const float*)d_in[17];
  const float* m_w1   = (const float*)d_in[18];
  const float* m_b1   = (const float*)d_in[19];
  const float* m_g1   = (const float*)d_in[20];
  const float* m_be1  = (const float*)d_in[21];
  const float* m_w2   = (const float*)d_in[22];
  const float* m_b2   = (const float*)d_in[23];
  const float* m_g2   = (const float*)d_in[24];
  const float* m_be2  = (const float*)d_in[25];
  const float* m_w3   = (const float*)d_in[26];
  const float* m_b3   = (const float*)d_in[27];
  const int*   eidx   = (const int*)d_in[28];
  const int*   batch  = (const int*)d_in[29];
  float* outp = (float*)d_out;

  const int NN = in_sizes[29];
  const int NE = in_sizes[1] / 2;
  const int NB = out_size;

  float* ws = (float*)d_ws;
  float*  h0   = ws;                                  // NN*64 f32
  float*  h1   = h0 + (size_t)NN * 64;                // NN*64 f32
  float*  gbuf = h1 + (size_t)NN * 64;                // NB*64 f32
  float*  cnt  = gbuf + (size_t)NB * 64;              // NB f32
  ushort* wt   = (ushort*)(cnt + NB);                 // 3*64*96 bf16
  ushort* hb0  = wt + 3 * 64 * 96;                    // NN*64 bf16
  ushort* hb1  = hb0 + (size_t)NN * 64;               // NN*64 bf16
  int*    csr  = (int*)(hb1 + (size_t)NN * 64);       // NN int
  int2*   edata= (int2*)(csr + NN);                   // NE int2

  hipMemsetAsync(gbuf, 0, sizeof(float) * ((size_t)NB * 64 + NB), stream);
  hipMemsetAsync(csr, 0, sizeof(int) * (size_t)NN, stream);

  const dim3 blk(256);
  k_prep_w<<<(3 * 64 * 96 + 255) / 256, blk, 0, stream>>>(conv_w, wt);
  k_node_embed<<<2048, blk, 0, stream>>>(x, ne_w1, ne_b1, ne_g1, ne_be1,
                                         ne_w2, ne_b2, ne_g2, ne_be2, h0, hb0, NN);
  k_hist<<<(NE + 255) / 256, blk, 0, stream>>>(eidx, csr, NE);
  k_scan_fast<<<1, 1024, 0, stream>>>(csr, NN);
  k_scatter<<<(NE + 255) / 256, blk, 0, stream>>>(eidx, ea, csr, edata, NE);

  float* hin = h0;  float* hout = h1;
  ushort* hbin = hb0; ushort* hbout = hb1;
  for (int l = 0; l < 3; l++) {
    k_edge_node<<<4096, blk, 0, stream>>>(
        hin, hbin, hout, hbout, edata, csr, wt + (size_t)l * 64 * 96,
        conv_b + l * 64, conv_mg + l * 64, conv_mb + l * 64,
        conv_ng + l * 64, conv_nb + l * 64,
        out_ng + l * 64, out_nb + l * 64, NN);
    float* tf = hin; hin = hout; hout = tf;
    ushort* tb = hbin; hbin = hbout; hbout = tb;
  }

  {
    const int chunk = 64;
    const int nwaves = (NN + chunk - 1) / chunk;
    const int nblocks = (nwaves * 64 + 255) / 256;
    k_pool_seg<<<nblocks, blk, 0, stream>>>(hin, batch, gbuf, cnt, NN, chunk);
  }
  k_head<<<(NB + 3) / 4, blk, 0, stream>>>(gbuf, cnt, m_w1, m_b1, m_g1, m_be1,
                                           m_w2, m_b2, m_g2, m_be2, m_w3, m_b3,
                                           outp, NB);
}

// Round 7
// 1085.170 us; speedup vs baseline: 1.5133x; 1.0211x over previous
//
#include <hip/hip_runtime.h>
#include <math.h>

// ---------------------------------------------------------------------------
// VertexGNN on MI355X — round 6 (r5 + compile fix: exp2f builtin).
// - merged init kernel (prep_w + node_embed + zero csr + zero gbuf/cnt):
//   12 -> 9 dispatches (tests the ~38us/dispatch overhead hypothesis).
// - edge kernel: 2-stage software pipeline (edata + gather prefetched behind
//   the LN/GELU epilogue), weights in LDS (ds_read_b128 per chunk), 3-term
//   A&S erf, fmaf-folded LN apply.
// ---------------------------------------------------------------------------

typedef __attribute__((ext_vector_type(8))) short bfrag;   // 8 x bf16
typedef __attribute__((ext_vector_type(4))) float ffrag;   // 4 x f32

__device__ __forceinline__ float wave_sum64(float v) {
#pragma unroll
  for (int m = 1; m < 64; m <<= 1) v += __shfl_xor(v, m, 64);
  return v;
}

__device__ __forceinline__ float rsum16(float v) {
#pragma unroll
  for (int m = 1; m < 16; m <<= 1) v += __shfl_xor(v, m, 64);
  return v;
}

__device__ __forceinline__ float ln_apply(float t, float g, float b) {
  float mu = wave_sum64(t) * 0.015625f;
  float d = t - mu;
  float var = wave_sum64(d * d) * 0.015625f;
  return d * rsqrtf(var + 1e-5f) * g + b;
}

// 3-term A&S 7.1.25 erf, |err| <= 2.5e-5; exp via hw v_exp_f32 (2^x)
__device__ __forceinline__ float erf_fast(float x) {
  float ax = fabsf(x);
  float t = __builtin_amdgcn_rcpf(fmaf(0.47047f, ax, 1.0f));
  float p = t * fmaf(t, fmaf(t, 0.7478556f, -0.0958798f), 0.3480242f);
  float e = __builtin_amdgcn_exp2f(-ax * ax * 1.4426950408889634f);
  float r = fmaf(-p, e, 1.0f);
  return copysignf(r, x);
}

__device__ __forceinline__ float gelu_exact(float v) {
  float half = 0.5f * v;
  return fmaf(half, erf_fast(v * 0.70710678118654752440f), half);
}

__device__ __forceinline__ float lane_bcast(float v, int k) {
  return __uint_as_float(__builtin_amdgcn_readlane(__float_as_uint(v), k));
}

// float -> bf16 (RNE)
__device__ __forceinline__ short f2bf(float f) {
  union { float f; unsigned u; } v; v.f = f;
  unsigned r = v.u + 0x7fffu + ((v.u >> 16) & 1u);
  return (short)(r >> 16);
}

// ------------------- merged init: prep_w | zero csr | zero g | embed -------
__global__ __launch_bounds__(256) void k_init(
    const float* __restrict__ x,
    const float* __restrict__ w1, const float* __restrict__ b1,
    const float* __restrict__ g1, const float* __restrict__ be1,
    const float* __restrict__ w2, const float* __restrict__ b2,
    const float* __restrict__ g2, const float* __restrict__ be2,
    const float* __restrict__ conv_w, ushort* __restrict__ wt,
    int* __restrict__ csr, float* __restrict__ gz,
    float* __restrict__ h, ushort* __restrict__ hb,
    int n_nodes, int nzero_g, int oZ1, int oZ2, int oEmb, int embWaves) {
  const int bid = blockIdx.x;
  const int tid = threadIdx.x;
  if (bid < oZ1) {  // prep_w: 3*64*96 = 18432 elems, 72 blocks
    const int i = bid * 256 + tid;
    const int k = i % 96, f = (i / 96) % 64, l = i / (96 * 64);
    const float v = (k < 66) ? conv_w[(size_t)l * 66 * 64 + k * 64 + f] : 0.0f;
    wt[i] = (ushort)f2bf(v);
    return;
  }
  if (bid < oZ2) {  // zero csr
    const int base = (bid - oZ1) * 1024;
    const int lim = min(base + 1024, n_nodes);
    for (int i = base + tid; i < lim; i += 256) csr[i] = 0;
    return;
  }
  if (bid < oEmb) {  // zero gbuf+cnt
    const int base = (bid - oZ2) * 1024;
    const int lim = min(base + 1024, nzero_g);
    for (int i = base + tid; i < lim; i += 256) gz[i] = 0.0f;
    return;
  }
  // ---- node embedding ----
  const int lane = tid & 63;
  const int wid = ((bid - oEmb) * 256 + tid) >> 6;
  const int nw = embWaves;
  float wc[64];
#pragma unroll
  for (int k = 0; k < 64; k++) wc[k] = w2[k * 64 + lane];
  const float w1a = w1[lane], w1b = w1[64 + lane];
  const float vb1 = b1[lane], vg1 = g1[lane], vbe1 = be1[lane];
  const float vb2 = b2[lane], vg2 = g2[lane], vbe2 = be2[lane];
  for (int n = wid; n < n_nodes; n += nw) {
    const float x0 = x[2 * n], x1 = x[2 * n + 1];
    float t = fmaf(x0, w1a, fmaf(x1, w1b, vb1));
    t = gelu_exact(ln_apply(t, vg1, vbe1));
    float a0 = vb2, a1 = 0.f, a2 = 0.f, a3 = 0.f;
#pragma unroll
    for (int k = 0; k < 64; k += 4) {
      a0 = fmaf(lane_bcast(t, k + 0), wc[k + 0], a0);
      a1 = fmaf(lane_bcast(t, k + 1), wc[k + 1], a1);
      a2 = fmaf(lane_bcast(t, k + 2), wc[k + 2], a2);
      a3 = fmaf(lane_bcast(t, k + 3), wc[k + 3], a3);
    }
    float acc = (a0 + a1) + (a2 + a3);
    acc = gelu_exact(ln_apply(acc, vg2, vbe2));
    h[n * 64 + lane] = acc;
    hb[n * 64 + lane] = (ushort)f2bf(acc);
  }
}

// ----------------------------- CSR build -----------------------------------
__global__ void k_hist(const int* __restrict__ ei, int* __restrict__ cnts, int ne) {
  int i = blockIdx.x * blockDim.x + threadIdx.x;
  if (i < ne) atomicAdd(&cnts[ei[ne + i]], 1);
}

__global__ __launch_bounds__(1024) void k_scan_fast(int* __restrict__ buf, int n) {
  __shared__ int wsum[16];
  const int tid = threadIdx.x, lane = tid & 63, w = tid >> 6;
  const int chunk = (n + 1023) / 1024;
  const int a = min(tid * chunk, n), b = min(a + chunk, n);
  int s = 0;
  for (int i = a; i < b; i++) s += buf[i];
  int inc = s;
#pragma unroll
  for (int sh = 1; sh < 64; sh <<= 1) {
    int t = __shfl_up(inc, sh, 64);
    if (lane >= sh) inc += t;
  }
  if (lane == 63) wsum[w] = inc;
  __syncthreads();
  int wb = 0;
  for (int j = 0; j < w; j++) wb += wsum[j];
  int excl = wb + inc - s;
  for (int i = a; i < b; i++) { int v = buf[i]; buf[i] = excl; excl += v; }
}

__global__ void k_scatter(const int* __restrict__ ei, const float* __restrict__ ea,
                          int* __restrict__ cursor, int2* __restrict__ edata, int ne) {
  int i = blockIdx.x * blockDim.x + threadIdx.x;
  if (i < ne) {
    const int d = ei[ne + i];
    const int s = ei[i];
    const float2 eav = *(const float2*)(ea + 2 * (size_t)i);
    const unsigned pk = (unsigned)(ushort)f2bf(eav.x) |
                        ((unsigned)(ushort)f2bf(eav.y) << 16);
    const int pos = atomicAdd(&cursor[d], 1);
    edata[pos] = make_int2(s, (int)pk);
  }
}

// ---------------- fused edge-message + aggregate + node update --------------
__global__ __launch_bounds__(256) void k_edge_node(
    const float* __restrict__ h_in, const ushort* __restrict__ hb_in,
    float* __restrict__ h_out, ushort* __restrict__ hb_out,
    const int2* __restrict__ edata, const int* __restrict__ ends,
    const ushort* __restrict__ wt,
    const float* __restrict__ bias, const float* __restrict__ mg,
    const float* __restrict__ mb,
    const float* __restrict__ ng, const float* __restrict__ nb,
    const float* __restrict__ og, const float* __restrict__ ob,
    int n_nodes) {
  __shared__ __align__(16) ushort lwt[64 * 96];   // 12 KB: B^T tiles
  {
    const uint4* s = (const uint4*)wt;
    uint4* d = (uint4*)lwt;
    for (int i = threadIdx.x; i < 768; i += 256) d[i] = s[i];
  }
  __syncthreads();

  const int lane = threadIdx.x & 63;
  const int grp = lane >> 4, col = lane & 15;
  const int wid = (blockIdx.x * blockDim.x + threadIdx.x) >> 6;
  const int nw = (gridDim.x * blockDim.x) >> 6;

  float vb[4], vg[4], vbb[4];
#pragma unroll
  for (int t = 0; t < 4; t++) {
    const int f = t * 16 + col;
    vb[t] = bias[f]; vg[t] = mg[f]; vbb[t] = mb[f];
  }

  for (int n = wid; n < n_nodes; n += nw) {
    const int start = (n == 0) ? 0 : ends[n - 1];
    const int end = ends[n];
    float aggf[4] = {0.f, 0.f, 0.f, 0.f};

    int p = start;
    int2 ed = edata[p + min(col, end - p - 1)];
    const ushort* hp0 = hb_in + (size_t)ed.x * 64 + grp * 8;
    bfrag A0 = *(const bfrag*)(hp0);
    bfrag A1 = *(const bfrag*)(hp0 + 32);
    int edy = ed.y;

    for (;;) {
      const int rem = min(16, end - p);
      const int pn = p + 16;
      const bool more = pn < end;
      // prefetch next chunk's payload (safe index when last chunk)
      const int nidx = more ? (pn + min(col, end - pn - 1)) : (p + min(col, rem - 1));
      const int2 edn = edata[nidx];

      bfrag A2 = {0, 0, 0, 0, 0, 0, 0, 0};
      if (grp == 0) {
        A2[0] = (short)(edy & 0xffff);
        A2[1] = (short)((unsigned)edy >> 16);
      }

      ffrag acc[4];
#pragma unroll
      for (int t = 0; t < 4; t++) { ffrag c = {vb[t], vb[t], vb[t], vb[t]}; acc[t] = c; }
#pragma unroll
      for (int t = 0; t < 4; t++) {
        const bfrag B = *(const bfrag*)(lwt + (t * 16 + col) * 96 + grp * 8);
        acc[t] = __builtin_amdgcn_mfma_f32_16x16x32_bf16(A0, B, acc[t], 0, 0, 0);
      }
#pragma unroll
      for (int t = 0; t < 4; t++) {
        const bfrag B = *(const bfrag*)(lwt + (t * 16 + col) * 96 + 32 + grp * 8);
        acc[t] = __builtin_amdgcn_mfma_f32_16x16x32_bf16(A1, B, acc[t], 0, 0, 0);
      }
#pragma unroll
      for (int t = 0; t < 4; t++) {
        const bfrag B = *(const bfrag*)(lwt + (t * 16 + col) * 96 + 64 + grp * 8);
        acc[t] = __builtin_amdgcn_mfma_f32_16x16x32_bf16(A2, B, acc[t], 0, 0, 0);
      }

      // prefetch next chunk's gather so it flies during the epilogue
      const ushort* hq = hb_in + (size_t)edn.x * 64 + grp * 8;
      const bfrag N0 = *(const bfrag*)(hq);
      const bfrag N1 = *(const bfrag*)(hq + 32);

      // ---- per-edge LayerNorm stats (rows m = grp*4+r) ----
      float mu[4], inv[4];
#pragma unroll
      for (int r = 0; r < 4; r++) {
        float s = (acc[0][r] + acc[1][r]) + (acc[2][r] + acc[3][r]);
        mu[r] = rsum16(s) * 0.015625f;
      }
#pragma unroll
      for (int r = 0; r < 4; r++) {
        float d0 = acc[0][r] - mu[r], d1 = acc[1][r] - mu[r];
        float d2 = acc[2][r] - mu[r], d3 = acc[3][r] - mu[r];
        float q = fmaf(d0, d0, fmaf(d1, d1, fmaf(d2, d2, d3 * d3)));
        inv[r] = rsqrtf(rsum16(q) * 0.015625f + 1e-5f);
      }

      // ---- LN-apply + GELU + masked in-register row-sum ----
#pragma unroll
      for (int t = 0; t < 4; t++) {
        float rs = 0.f;
#pragma unroll
        for (int r = 0; r < 4; r++) {
          const float s = inv[r] * vg[t];
          float v = fmaf(acc[t][r] - mu[r], s, vbb[t]);
          v = gelu_exact(v);
          rs += (grp * 4 + r < rem) ? v : 0.f;
        }
        rs += __shfl_xor(rs, 16, 64);
        rs += __shfl_xor(rs, 32, 64);
        aggf[t] += rs;
      }

      if (!more) break;
      p = pn; A0 = N0; A1 = N1; edy = edn.y;
    }

    // agg in feature=lane layout (lane = grp*16+col holds tile t=grp)
    const float aggl = (grp == 0) ? aggf[0] : (grp == 1) ? aggf[1]
                     : (grp == 2) ? aggf[2] : aggf[3];

    const float dg = fmaxf((float)(end - start), 1.0f);
    const float hv = h_in[(size_t)n * 64 + lane];
    const float a = aggl / dg + hv;
    const float c = ln_apply(a, ng[lane], nb[lane]);
    const float o = ln_apply(c, og[lane], ob[lane]);
    const float outv = hv + o;
    h_out[(size_t)n * 64 + lane] = outv;
    hb_out[(size_t)n * 64 + lane] = (ushort)f2bf(outv);
  }
}

// ------------------------------ pooling (segmented) -------------------------
__global__ void k_pool_seg(const float* __restrict__ h, const int* __restrict__ batch,
                           float* __restrict__ g, float* __restrict__ cnt,
                           int n_nodes, int chunk) {
  const int lane = threadIdx.x & 63;
  const int wid = (blockIdx.x * blockDim.x + threadIdx.x) >> 6;
  const int n0 = wid * chunk;
  if (n0 >= n_nodes) return;
  const int n1 = min(n0 + chunk, n_nodes);
  int cur = batch[n0], c = 0;
  float acc = 0.f;
  for (int n = n0; n < n1; n++) {
    const int b = batch[n];
    if (b != cur) {
      atomicAdd(&g[(size_t)cur * 64 + lane], acc);
      if (lane == 0) atomicAdd(&cnt[cur], (float)c);
      acc = 0.f; c = 0; cur = b;
    }
    acc += h[(size_t)n * 64 + lane];
    c++;
  }
  atomicAdd(&g[(size_t)cur * 64 + lane], acc);
  if (lane == 0) atomicAdd(&cnt[cur], (float)c);
}

// ------------------------------- head --------------------------------------
__global__ void k_head(const float* __restrict__ g, const float* __restrict__ cnt,
                       const float* __restrict__ w1, const float* __restrict__ b1,
                       const float* __restrict__ g1, const float* __restrict__ be1,
                       const float* __restrict__ w2, const float* __restrict__ b2,
                       const float* __restrict__ g2, const float* __restrict__ be2,
                       const float* __restrict__ w3, const float* __restrict__ b3,
                       float* __restrict__ out, int nb_) {
  const int lane = threadIdx.x & 63;
  const int row = (blockIdx.x * blockDim.x + threadIdx.x) >> 6;
  if (row >= nb_) return;
  const float c = fmaxf(cnt[row], 1.0f);
  const float gv = g[row * 64 + lane] / c;
  float a0 = b1[lane], a1 = 0.f, a2 = 0.f, a3 = 0.f;
#pragma unroll
  for (int k = 0; k < 64; k += 4) {
    a0 = fmaf(lane_bcast(gv, k + 0), w1[(k + 0) * 64 + lane], a0);
    a1 = fmaf(lane_bcast(gv, k + 1), w1[(k + 1) * 64 + lane], a1);
    a2 = fmaf(lane_bcast(gv, k + 2), w1[(k + 2) * 64 + lane], a2);
    a3 = fmaf(lane_bcast(gv, k + 3), w1[(k + 3) * 64 + lane], a3);
  }
  float t = (a0 + a1) + (a2 + a3);
  t = fmaxf(ln_apply(t, g1[lane], be1[lane]), 0.0f);

  const int j = lane & 31;
  float c0 = b2[j], c1 = 0.f, c2 = 0.f, c3 = 0.f;
#pragma unroll
  for (int k = 0; k < 64; k += 4) {
    c0 = fmaf(lane_bcast(t, k + 0), w2[(k + 0) * 32 + j], c0);
    c1 = fmaf(lane_bcast(t, k + 1), w2[(k + 1) * 32 + j], c1);
    c2 = fmaf(lane_bcast(t, k + 2), w2[(k + 2) * 32 + j], c2);
    c3 = fmaf(lane_bcast(t, k + 3), w2[(k + 3) * 32 + j], c3);
  }
  float t2 = (c0 + c1) + (c2 + c3);
  t2 = fmaxf(ln_apply(t2, g2[j], be2[j]), 0.0f);
  const float p = t2 * w3[j];
  const float s = wave_sum64(p) * 0.5f;
  if (lane == 0) out[row] = s + b3[0];
}

// ---------------------------------------------------------------------------
extern "C" void kernel_launch(void* const* d_in, const int* in_sizes, int n_in,
                              void* d_out, int out_size, void* d_ws, size_t ws_size,
                              hipStream_t stream) {
  const float* x      = (const float*)d_in[0];
  const float* ea     = (const float*)d_in[1];
  const float* ne_w1  = (const float*)d_in[2];
  const float* ne_b1  = (const float*)d_in[3];
  const float* ne_g1  = (const float*)d_in[4];
  const float* ne_be1 = (const float*)d_in[5];
  const float* ne_w2  = (const float*)d_in[6];
  const float* ne_b2  = (const float*)d_in[7];
  const float* ne_g2  = (const float*)d_in[8];
  const float* ne_be2 = (const float*)d_in[9];
  const float* conv_w = (const float*)d_in[10];
  const float* conv_b = (const float*)d_in[11];
  const float* conv_mg= (const float*)d_in[12];
  const float* conv_mb= (const float*)d_in[13];
  const float* conv_ng= (const float*)d_in[14];
  const float* conv_nb= (const float*)d_in[15];
  const float* out_ng = (const float*)d_in[16];
  const float* out_nb = (const float*)d_in[17];
  const float* m_w1   = (const float*)d_in[18];
  const float* m_b1   = (const float*)d_in[19];
  const float* m_g1   = (const float*)d_in[20];
  const float* m_be1  = (const float*)d_in[21];
  const float* m_w2   = (const float*)d_in[22];
  const float* m_b2   = (const float*)d_in[23];
  const float* m_g2   = (const float*)d_in[24];
  const float* m_be2  = (const float*)d_in[25];
  const float* m_w3   = (const float*)d_in[26];
  const float* m_b3   = (const float*)d_in[27];
  const int*   eidx   = (const int*)d_in[28];
  const int*   batch  = (const int*)d_in[29];
  float* outp = (float*)d_out;

  const int NN = in_sizes[29];
  const int NE = in_sizes[1] / 2;
  const int NB = out_size;

  float* ws = (float*)d_ws;
  float*  h0   = ws;                                  // NN*64 f32
  float*  h1   = h0 + (size_t)NN * 64;                // NN*64 f32
  float*  gbuf = h1 + (size_t)NN * 64;                // NB*64 f32
  float*  cnt  = gbuf + (size_t)NB * 64;              // NB f32
  ushort* wt   = (ushort*)(cnt + NB);                 // 3*64*96 bf16
  ushort* hb0  = wt + 3 * 64 * 96;                    // NN*64 bf16
  ushort* hb1  = hb0 + (size_t)NN * 64;               // NN*64 bf16
  int*    csr  = (int*)(hb1 + (size_t)NN * 64);       // NN int
  int2*   edata= (int2*)(csr + NN);                   // NE int2

  const dim3 blk(256);

  // merged init: prep(72) | zero-csr | zero-gbuf/cnt | embed(1024 blocks)
  const int nPrep = (3 * 64 * 96) / 256;              // 72
  const int nZcsr = (NN + 1023) / 1024;
  const int nZg   = (NB * 64 + NB + 1023) / 1024;
  const int oZ1 = nPrep, oZ2 = nPrep + nZcsr, oEmb = nPrep + nZcsr + nZg;
  const int embBlocks = 1024;
  k_init<<<oEmb + embBlocks, blk, 0, stream>>>(
      x, ne_w1, ne_b1, ne_g1, ne_be1, ne_w2, ne_b2, ne_g2, ne_be2,
      conv_w, wt, csr, gbuf, h0, hb0, NN, NB * 64 + NB,
      oZ1, oZ2, oEmb, embBlocks * 4);

  k_hist<<<(NE + 255) / 256, blk, 0, stream>>>(eidx, csr, NE);
  k_scan_fast<<<1, 1024, 0, stream>>>(csr, NN);
  k_scatter<<<(NE + 255) / 256, blk, 0, stream>>>(eidx, ea, csr, edata, NE);

  float* hin = h0;  float* hout = h1;
  ushort* hbin = hb0; ushort* hbout = hb1;
  for (int l = 0; l < 3; l++) {
    k_edge_node<<<4096, blk, 0, stream>>>(
        hin, hbin, hout, hbout, edata, csr, wt + (size_t)l * 64 * 96,
        conv_b + l * 64, conv_mg + l * 64, conv_mb + l * 64,
        conv_ng + l * 64, conv_nb + l * 64,
        out_ng + l * 64, out_nb + l * 64, NN);
    float* tf = hin; hin = hout; hout = tf;
    ushort* tb = hbin; hbin = hbout; hbout = tb;
  }

  {
    const int chunk = 32;
    const int nwaves = (NN + chunk - 1) / chunk;
    const int nblocks = (nwaves * 64 + 255) / 256;
    k_pool_seg<<<nblocks, blk, 0, stream>>>(hin, batch, gbuf, cnt, NN, chunk);
  }
  k_head<<<(NB + 3) / 4, blk, 0, stream>>>(gbuf, cnt, m_w1, m_b1, m_g1, m_be1,
                                           m_w2, m_b2, m_g2, m_be2, m_w3, m_b3,
                                           outp, NB);
}

// Round 8
// 944.163 us; speedup vs baseline: 1.7393x; 1.1493x over previous
//
#include <hip/hip_runtime.h>
#include <math.h>

// ---------------------------------------------------------------------------
// VertexGNN on MI355X — round 7:
// - k_edge_node: __launch_bounds__(256,4) to lift register-capped occupancy
//   (Occ% tracked 1/VGPR across R1-R6: unified-file AGPRs are the cap);
//   E[x^2] LN stats, float-mask row-sum, 2-fma LN apply.
// - k_scan_fast: int4-vectorized single-block scan.
// ---------------------------------------------------------------------------

typedef __attribute__((ext_vector_type(8))) short bfrag;   // 8 x bf16
typedef __attribute__((ext_vector_type(4))) float ffrag;   // 4 x f32

__device__ __forceinline__ float wave_sum64(float v) {
#pragma unroll
  for (int m = 1; m < 64; m <<= 1) v += __shfl_xor(v, m, 64);
  return v;
}

__device__ __forceinline__ float rsum16(float v) {
#pragma unroll
  for (int m = 1; m < 16; m <<= 1) v += __shfl_xor(v, m, 64);
  return v;
}

__device__ __forceinline__ float ln_apply(float t, float g, float b) {
  float mu = wave_sum64(t) * 0.015625f;
  float d = t - mu;
  float var = wave_sum64(d * d) * 0.015625f;
  return d * rsqrtf(var + 1e-5f) * g + b;
}

// 3-term A&S 7.1.25 erf, |err| <= 2.5e-5; exp via hw v_exp_f32 (2^x)
__device__ __forceinline__ float erf_fast(float x) {
  float ax = fabsf(x);
  float t = __builtin_amdgcn_rcpf(fmaf(0.47047f, ax, 1.0f));
  float p = t * fmaf(t, fmaf(t, 0.7478556f, -0.0958798f), 0.3480242f);
  float e = __builtin_amdgcn_exp2f(-ax * ax * 1.4426950408889634f);
  float r = fmaf(-p, e, 1.0f);
  return copysignf(r, x);
}

__device__ __forceinline__ float gelu_exact(float v) {
  float half = 0.5f * v;
  return fmaf(half, erf_fast(v * 0.70710678118654752440f), half);
}

__device__ __forceinline__ float lane_bcast(float v, int k) {
  return __uint_as_float(__builtin_amdgcn_readlane(__float_as_uint(v), k));
}

// float -> bf16 (RNE)
__device__ __forceinline__ short f2bf(float f) {
  union { float f; unsigned u; } v; v.f = f;
  unsigned r = v.u + 0x7fffu + ((v.u >> 16) & 1u);
  return (short)(r >> 16);
}

// ------------------- merged init: prep_w | zero csr | zero g | embed -------
__global__ __launch_bounds__(256) void k_init(
    const float* __restrict__ x,
    const float* __restrict__ w1, const float* __restrict__ b1,
    const float* __restrict__ g1, const float* __restrict__ be1,
    const float* __restrict__ w2, const float* __restrict__ b2,
    const float* __restrict__ g2, const float* __restrict__ be2,
    const float* __restrict__ conv_w, ushort* __restrict__ wt,
    int* __restrict__ csr, float* __restrict__ gz,
    float* __restrict__ h, ushort* __restrict__ hb,
    int n_nodes, int nzero_g, int oZ1, int oZ2, int oEmb, int embWaves) {
  const int bid = blockIdx.x;
  const int tid = threadIdx.x;
  if (bid < oZ1) {  // prep_w: 3*64*96 = 18432 elems, 72 blocks
    const int i = bid * 256 + tid;
    const int k = i % 96, f = (i / 96) % 64, l = i / (96 * 64);
    const float v = (k < 66) ? conv_w[(size_t)l * 66 * 64 + k * 64 + f] : 0.0f;
    wt[i] = (ushort)f2bf(v);
    return;
  }
  if (bid < oZ2) {  // zero csr
    const int base = (bid - oZ1) * 1024;
    const int lim = min(base + 1024, n_nodes);
    for (int i = base + tid; i < lim; i += 256) csr[i] = 0;
    return;
  }
  if (bid < oEmb) {  // zero gbuf+cnt
    const int base = (bid - oZ2) * 1024;
    const int lim = min(base + 1024, nzero_g);
    for (int i = base + tid; i < lim; i += 256) gz[i] = 0.0f;
    return;
  }
  // ---- node embedding ----
  const int lane = tid & 63;
  const int wid = ((bid - oEmb) * 256 + tid) >> 6;
  const int nw = embWaves;
  float wc[64];
#pragma unroll
  for (int k = 0; k < 64; k++) wc[k] = w2[k * 64 + lane];
  const float w1a = w1[lane], w1b = w1[64 + lane];
  const float vb1 = b1[lane], vg1 = g1[lane], vbe1 = be1[lane];
  const float vb2 = b2[lane], vg2 = g2[lane], vbe2 = be2[lane];
  for (int n = wid; n < n_nodes; n += nw) {
    const float x0 = x[2 * n], x1 = x[2 * n + 1];
    float t = fmaf(x0, w1a, fmaf(x1, w1b, vb1));
    t = gelu_exact(ln_apply(t, vg1, vbe1));
    float a0 = vb2, a1 = 0.f, a2 = 0.f, a3 = 0.f;
#pragma unroll
    for (int k = 0; k < 64; k += 4) {
      a0 = fmaf(lane_bcast(t, k + 0), wc[k + 0], a0);
      a1 = fmaf(lane_bcast(t, k + 1), wc[k + 1], a1);
      a2 = fmaf(lane_bcast(t, k + 2), wc[k + 2], a2);
      a3 = fmaf(lane_bcast(t, k + 3), wc[k + 3], a3);
    }
    float acc = (a0 + a1) + (a2 + a3);
    acc = gelu_exact(ln_apply(acc, vg2, vbe2));
    h[n * 64 + lane] = acc;
    hb[n * 64 + lane] = (ushort)f2bf(acc);
  }
}

// ----------------------------- CSR build -----------------------------------
__global__ void k_hist(const int* __restrict__ ei, int* __restrict__ cnts, int ne) {
  int i = blockIdx.x * blockDim.x + threadIdx.x;
  if (i < ne) atomicAdd(&cnts[ei[ne + i]], 1);
}

// Single-block exclusive scan, int4-vectorized chunks, ~3 barriers total.
__global__ __launch_bounds__(1024) void k_scan_fast(int* __restrict__ buf, int n) {
  __shared__ int wsum[16];
  const int tid = threadIdx.x, lane = tid & 63, w = tid >> 6;
  const int chunk = (((n + 1023) / 1024) + 3) & ~3;   // multiple of 4
  const int a = min(tid * chunk, n), b = min(a + chunk, n);
  const bool full = (a + chunk <= n);
  int s = 0;
  if (full) {
    const int4* p4 = (const int4*)(buf + a);
#pragma unroll 4
    for (int i = 0; i < chunk / 4; i++) {
      int4 v = p4[i];
      s += v.x + v.y + v.z + v.w;
    }
  } else {
    for (int i = a; i < b; i++) s += buf[i];
  }
  int inc = s;
#pragma unroll
  for (int sh = 1; sh < 64; sh <<= 1) {
    int t = __shfl_up(inc, sh, 64);
    if (lane >= sh) inc += t;
  }
  if (lane == 63) wsum[w] = inc;
  __syncthreads();
  int wb = 0;
  for (int j = 0; j < w; j++) wb += wsum[j];
  int excl = wb + inc - s;
  if (full) {
    int4* p4 = (int4*)(buf + a);
#pragma unroll 4
    for (int i = 0; i < chunk / 4; i++) {
      int4 v = p4[i];
      int4 o;
      o.x = excl; excl += v.x;
      o.y = excl; excl += v.y;
      o.z = excl; excl += v.z;
      o.w = excl; excl += v.w;
      p4[i] = o;
    }
  } else {
    for (int i = a; i < b; i++) { int v = buf[i]; buf[i] = excl; excl += v; }
  }
}

__global__ void k_scatter(const int* __restrict__ ei, const float* __restrict__ ea,
                          int* __restrict__ cursor, int2* __restrict__ edata, int ne) {
  int i = blockIdx.x * blockDim.x + threadIdx.x;
  if (i < ne) {
    const int d = ei[ne + i];
    const int s = ei[i];
    const float2 eav = *(const float2*)(ea + 2 * (size_t)i);
    const unsigned pk = (unsigned)(ushort)f2bf(eav.x) |
                        ((unsigned)(ushort)f2bf(eav.y) << 16);
    const int pos = atomicAdd(&cursor[d], 1);
    edata[pos] = make_int2(s, (int)pk);
  }
}

// ---------------- fused edge-message + aggregate + node update --------------
__global__ __launch_bounds__(256, 4) void k_edge_node(
    const float* __restrict__ h_in, const ushort* __restrict__ hb_in,
    float* __restrict__ h_out, ushort* __restrict__ hb_out,
    const int2* __restrict__ edata, const int* __restrict__ ends,
    const ushort* __restrict__ wt,
    const float* __restrict__ bias, const float* __restrict__ mg,
    const float* __restrict__ mb,
    const float* __restrict__ ng, const float* __restrict__ nb,
    const float* __restrict__ og, const float* __restrict__ ob,
    int n_nodes) {
  __shared__ __align__(16) ushort lwt[64 * 96];   // 12 KB: B^T tiles
  {
    const uint4* s = (const uint4*)wt;
    uint4* d = (uint4*)lwt;
    for (int i = threadIdx.x; i < 768; i += 256) d[i] = s[i];
  }
  __syncthreads();

  const int lane = threadIdx.x & 63;
  const int grp = lane >> 4, col = lane & 15;
  const int wid = (blockIdx.x * blockDim.x + threadIdx.x) >> 6;
  const int nw = (gridDim.x * blockDim.x) >> 6;

  float vb[4], vg[4], vbb[4];
#pragma unroll
  for (int t = 0; t < 4; t++) {
    const int f = t * 16 + col;
    vb[t] = bias[f]; vg[t] = mg[f]; vbb[t] = mb[f];
  }

  for (int n = wid; n < n_nodes; n += nw) {
    const int start = (n == 0) ? 0 : ends[n - 1];
    const int end = ends[n];
    float aggf[4] = {0.f, 0.f, 0.f, 0.f};

    int p = start;
    int2 ed = edata[p + min(col, end - p - 1)];
    const ushort* hp0 = hb_in + (size_t)ed.x * 64 + grp * 8;
    bfrag A0 = *(const bfrag*)(hp0);
    bfrag A1 = *(const bfrag*)(hp0 + 32);
    int edy = ed.y;

    for (;;) {
      const int rem = min(16, end - p);
      const int pn = p + 16;
      const bool more = pn < end;
      // prefetch next chunk's payload (safe index when last chunk)
      const int nidx = more ? (pn + min(col, end - pn - 1)) : (p + min(col, rem - 1));
      const int2 edn = edata[nidx];

      bfrag A2 = {0, 0, 0, 0, 0, 0, 0, 0};
      if (grp == 0) {
        A2[0] = (short)(edy & 0xffff);
        A2[1] = (short)((unsigned)edy >> 16);
      }

      ffrag acc[4];
#pragma unroll
      for (int t = 0; t < 4; t++) { ffrag c = {vb[t], vb[t], vb[t], vb[t]}; acc[t] = c; }
#pragma unroll
      for (int t = 0; t < 4; t++) {
        const bfrag B = *(const bfrag*)(lwt + (t * 16 + col) * 96 + grp * 8);
        acc[t] = __builtin_amdgcn_mfma_f32_16x16x32_bf16(A0, B, acc[t], 0, 0, 0);
      }
#pragma unroll
      for (int t = 0; t < 4; t++) {
        const bfrag B = *(const bfrag*)(lwt + (t * 16 + col) * 96 + 32 + grp * 8);
        acc[t] = __builtin_amdgcn_mfma_f32_16x16x32_bf16(A1, B, acc[t], 0, 0, 0);
      }
#pragma unroll
      for (int t = 0; t < 4; t++) {
        const bfrag B = *(const bfrag*)(lwt + (t * 16 + col) * 96 + 64 + grp * 8);
        acc[t] = __builtin_amdgcn_mfma_f32_16x16x32_bf16(A2, B, acc[t], 0, 0, 0);
      }

      // prefetch next chunk's gather so it flies during the epilogue
      const ushort* hq = hb_in + (size_t)edn.x * 64 + grp * 8;
      const bfrag N0 = *(const bfrag*)(hq);
      const bfrag N1 = *(const bfrag*)(hq + 32);

      // ---- per-edge LN stats via E[x] / E[x^2] (rows m = grp*4+r) ----
      float sx[4], sq[4];
#pragma unroll
      for (int r = 0; r < 4; r++) {
        float s = (acc[0][r] + acc[1][r]) + (acc[2][r] + acc[3][r]);
        float q = fmaf(acc[0][r], acc[0][r], fmaf(acc[1][r], acc[1][r],
                  fmaf(acc[2][r], acc[2][r], acc[3][r] * acc[3][r])));
        sx[r] = s; sq[r] = q;
      }
#pragma unroll
      for (int r = 0; r < 4; r++) sx[r] = rsum16(sx[r]);
#pragma unroll
      for (int r = 0; r < 4; r++) sq[r] = rsum16(sq[r]);
      // per-row scale (iv) and shift (mi = -mu*iv), row-valid float mask
      float iv[4], mi[4], mk[4];
#pragma unroll
      for (int r = 0; r < 4; r++) {
        const float mu = sx[r] * 0.015625f;
        const float var = fmaf(-mu, mu, sq[r] * 0.015625f);
        iv[r] = rsqrtf(var + 1e-5f);
        mi[r] = -mu * iv[r];
        mk[r] = (grp * 4 + r < rem) ? 1.0f : 0.0f;
      }

      // ---- LN-apply (2 fma) + GELU + float-masked row-sum ----
#pragma unroll
      for (int t = 0; t < 4; t++) {
        float rs = 0.f;
#pragma unroll
        for (int r = 0; r < 4; r++) {
          const float z = fmaf(acc[t][r], iv[r], mi[r]);
          float v = fmaf(z, vg[t], vbb[t]);
          v = gelu_exact(v);
          rs = fmaf(v, mk[r], rs);
        }
        rs += __shfl_xor(rs, 16, 64);
        rs += __shfl_xor(rs, 32, 64);
        aggf[t] += rs;
      }

      if (!more) break;
      p = pn; A0 = N0; A1 = N1; edy = edn.y;
    }

    // agg in feature=lane layout (lane = grp*16+col holds tile t=grp)
    const float aggl = (grp == 0) ? aggf[0] : (grp == 1) ? aggf[1]
                     : (grp == 2) ? aggf[2] : aggf[3];

    const float dg = fmaxf((float)(end - start), 1.0f);
    const float hv = h_in[(size_t)n * 64 + lane];
    const float a = aggl / dg + hv;
    const float c = ln_apply(a, ng[lane], nb[lane]);
    const float o = ln_apply(c, og[lane], ob[lane]);
    const float outv = hv + o;
    h_out[(size_t)n * 64 + lane] = outv;
    hb_out[(size_t)n * 64 + lane] = (ushort)f2bf(outv);
  }
}

// ------------------------------ pooling (segmented) -------------------------
__global__ void k_pool_seg(const float* __restrict__ h, const int* __restrict__ batch,
                           float* __restrict__ g, float* __restrict__ cnt,
                           int n_nodes, int chunk) {
  const int lane = threadIdx.x & 63;
  const int wid = (blockIdx.x * blockDim.x + threadIdx.x) >> 6;
  const int n0 = wid * chunk;
  if (n0 >= n_nodes) return;
  const int n1 = min(n0 + chunk, n_nodes);
  int cur = batch[n0], c = 0;
  float acc = 0.f;
  for (int n = n0; n < n1; n++) {
    const int b = batch[n];
    if (b != cur) {
      atomicAdd(&g[(size_t)cur * 64 + lane], acc);
      if (lane == 0) atomicAdd(&cnt[cur], (float)c);
      acc = 0.f; c = 0; cur = b;
    }
    acc += h[(size_t)n * 64 + lane];
    c++;
  }
  atomicAdd(&g[(size_t)cur * 64 + lane], acc);
  if (lane == 0) atomicAdd(&cnt[cur], (float)c);
}

// ------------------------------- head --------------------------------------
__global__ void k_head(const float* __restrict__ g, const float* __restrict__ cnt,
                       const float* __restrict__ w1, const float* __restrict__ b1,
                       const float* __restrict__ g1, const float* __restrict__ be1,
                       const float* __restrict__ w2, const float* __restrict__ b2,
                       const float* __restrict__ g2, const float* __restrict__ be2,
                       const float* __restrict__ w3, const float* __restrict__ b3,
                       float* __restrict__ out, int nb_) {
  const int lane = threadIdx.x & 63;
  const int row = (blockIdx.x * blockDim.x + threadIdx.x) >> 6;
  if (row >= nb_) return;
  const float c = fmaxf(cnt[row], 1.0f);
  const float gv = g[row * 64 + lane] / c;
  float a0 = b1[lane], a1 = 0.f, a2 = 0.f, a3 = 0.f;
#pragma unroll
  for (int k = 0; k < 64; k += 4) {
    a0 = fmaf(lane_bcast(gv, k + 0), w1[(k + 0) * 64 + lane], a0);
    a1 = fmaf(lane_bcast(gv, k + 1), w1[(k + 1) * 64 + lane], a1);
    a2 = fmaf(lane_bcast(gv, k + 2), w1[(k + 2) * 64 + lane], a2);
    a3 = fmaf(lane_bcast(gv, k + 3), w1[(k + 3) * 64 + lane], a3);
  }
  float t = (a0 + a1) + (a2 + a3);
  t = fmaxf(ln_apply(t, g1[lane], be1[lane]), 0.0f);

  const int j = lane & 31;
  float c0 = b2[j], c1 = 0.f, c2 = 0.f, c3 = 0.f;
#pragma unroll
  for (int k = 0; k < 64; k += 4) {
    c0 = fmaf(lane_bcast(t, k + 0), w2[(k + 0) * 32 + j], c0);
    c1 = fmaf(lane_bcast(t, k + 1), w2[(k + 1) * 32 + j], c1);
    c2 = fmaf(lane_bcast(t, k + 2), w2[(k + 2) * 32 + j], c2);
    c3 = fmaf(lane_bcast(t, k + 3), w2[(k + 3) * 32 + j], c3);
  }
  float t2 = (c0 + c1) + (c2 + c3);
  t2 = fmaxf(ln_apply(t2, g2[j], be2[j]), 0.0f);
  const float p = t2 * w3[j];
  const float s = wave_sum64(p) * 0.5f;
  if (lane == 0) out[row] = s + b3[0];
}

// ---------------------------------------------------------------------------
extern "C" void kernel_launch(void* const* d_in, const int* in_sizes, int n_in,
                              void* d_out, int out_size, void* d_ws, size_t ws_size,
                              hipStream_t stream) {
  const float* x      = (const float*)d_in[0];
  const float* ea     = (const float*)d_in[1];
  const float* ne_w1  = (const float*)d_in[2];
  const float* ne_b1  = (const float*)d_in[3];
  const float* ne_g1  = (const float*)d_in[4];
  const float* ne_be1 = (const float*)d_in[5];
  const float* ne_w2  = (const float*)d_in[6];
  const float* ne_b2  = (const float*)d_in[7];
  const float* ne_g2  = (const float*)d_in[8];
  const float* ne_be2 = (const float*)d_in[9];
  const float* conv_w = (const float*)d_in[10];
  const float* conv_b = (const float*)d_in[11];
  const float* conv_mg= (const float*)d_in[12];
  const float* conv_mb= (const float*)d_in[13];
  const float* conv_ng= (const float*)d_in[14];
  const float* conv_nb= (const float*)d_in[15];
  const float* out_ng = (const float*)d_in[16];
  const float* out_nb = (const float*)d_in[17];
  const float* m_w1   = (const float*)d_in[18];
  const float* m_b1   = (const float*)d_in[19];
  const float* m_g1   = (const float*)d_in[20];
  const float* m_be1  = (const float*)d_in[21];
  const float* m_w2   = (const float*)d_in[22];
  const float* m_b2   = (const float*)d_in[23];
  const float* m_g2   = (const float*)d_in[24];
  const float* m_be2  = (const float*)d_in[25];
  const float* m_w3   = (const float*)d_in[26];
  const float* m_b3   = (const float*)d_in[27];
  const int*   eidx   = (const int*)d_in[28];
  const int*   batch  = (const int*)d_in[29];
  float* outp = (float*)d_out;

  const int NN = in_sizes[29];
  const int NE = in_sizes[1] / 2;
  const int NB = out_size;

  float* ws = (float*)d_ws;
  float*  h0   = ws;                                  // NN*64 f32
  float*  h1   = h0 + (size_t)NN * 64;                // NN*64 f32
  float*  gbuf = h1 + (size_t)NN * 64;                // NB*64 f32
  float*  cnt  = gbuf + (size_t)NB * 64;              // NB f32
  ushort* wt   = (ushort*)(cnt + NB);                 // 3*64*96 bf16
  ushort* hb0  = wt + 3 * 64 * 96;                    // NN*64 bf16
  ushort* hb1  = hb0 + (size_t)NN * 64;               // NN*64 bf16
  int*    csr  = (int*)(hb1 + (size_t)NN * 64);       // NN int
  int2*   edata= (int2*)(csr + NN);                   // NE int2

  const dim3 blk(256);

  // merged init: prep(72) | zero-csr | zero-gbuf/cnt | embed(2048 blocks)
  const int nPrep = (3 * 64 * 96) / 256;              // 72
  const int nZcsr = (NN + 1023) / 1024;
  const int nZg   = (NB * 64 + NB + 1023) / 1024;
  const int oZ1 = nPrep, oZ2 = nPrep + nZcsr, oEmb = nPrep + nZcsr + nZg;
  const int embBlocks = 2048;
  k_init<<<oEmb + embBlocks, blk, 0, stream>>>(
      x, ne_w1, ne_b1, ne_g1, ne_be1, ne_w2, ne_b2, ne_g2, ne_be2,
      conv_w, wt, csr, gbuf, h0, hb0, NN, NB * 64 + NB,
      oZ1, oZ2, oEmb, embBlocks * 4);

  k_hist<<<(NE + 255) / 256, blk, 0, stream>>>(eidx, csr, NE);
  k_scan_fast<<<1, 1024, 0, stream>>>(csr, NN);
  k_scatter<<<(NE + 255) / 256, blk, 0, stream>>>(eidx, ea, csr, edata, NE);

  float* hin = h0;  float* hout = h1;
  ushort* hbin = hb0; ushort* hbout = hb1;
  for (int l = 0; l < 3; l++) {
    k_edge_node<<<4096, blk, 0, stream>>>(
        hin, hbin, hout, hbout, edata, csr, wt + (size_t)l * 64 * 96,
        conv_b + l * 64, conv_mg + l * 64, conv_mb + l * 64,
        conv_ng + l * 64, conv_nb + l * 64,
        out_ng + l * 64, out_nb + l * 64, NN);
    float* tf = hin; hin = hout; hout = tf;
    ushort* tb = hbin; hbin = hbout; hbout = tb;
  }

  {
    const int chunk = 32;
    const int nwaves = (NN + chunk - 1) / chunk;
    const int nblocks = (nwaves * 64 + 255) / 256;
    k_pool_seg<<<nblocks, blk, 0, stream>>>(hin, batch, gbuf, cnt, NN, chunk);
  }
  k_head<<<(NB + 3) / 4, blk, 0, stream>>>(gbuf, cnt, m_w1, m_b1, m_g1, m_be1,
                                           m_w2, m_b2, m_g2, m_be2, m_w3, m_b3,
                                           outp, NB);
}